// Round 12
// baseline (146.642 us; speedup 1.0000x reference)
//
#include <hip/hip_runtime.h>
#include <math.h>

#define BB 4
#define TT 1024
#define DD 512
#define HH 8
#define DHH 64

typedef short bf8_t __attribute__((ext_vector_type(8)));
typedef float f32x4 __attribute__((ext_vector_type(4)));

__device__ __forceinline__ float softplus_f(float z) {
    return fmaxf(z, 0.f) + log1pf(__expf(-fabsf(z)));
}

__device__ __forceinline__ unsigned short f2bf(float f) {
    union { float f; unsigned int u; } v; v.f = f;
    return (unsigned short)((v.u + 0x7FFFu + ((v.u >> 16) & 1u)) >> 16);
}

// Raw barrier: LDS visibility only — does NOT drain vmcnt.
__device__ __forceinline__ void bar_lgkm() {
    asm volatile("s_waitcnt lgkmcnt(0)" ::: "memory");
    __builtin_amdgcn_s_barrier();
}

// Fragment-major swizzled offsets (bijective within one bh's 65536 shorts):
//   off = st*4096 + nb*1024 + c*512 + lg*128 + lr*8 + e
// K frag: (s,dh):  st=s>>6, nb=(s>>4)&3, lr=s&15 | c=dh>>5, lg=(dh>>3)&3, e=dh&7
// V frag: (s,dh):  st=s>>6, c=(s>>5)&1, lg=(s>>3)&3, e=s&7 | nb=dh>>4, lr=dh&15
__device__ __forceinline__ int koff(int t, int dh) {
    return ((t >> 4) << 10) + ((t & 15) << 3) + ((dh >> 3) << 7) + (dh & 7);
}
__device__ __forceinline__ int voff(int s, int dh) {
    return ((s >> 6) << 12) + (((s >> 5) & 1) << 9) + (((s >> 3) & 3) << 7)
         + (s & 7) + ((dh >> 4) << 10) + ((dh & 15) << 3);
}

// ---------------------------------------------------------------------------
// K0: fused prep (cast x, transpose weights, f32 sigma). Unchanged from r9.
// ---------------------------------------------------------------------------
__global__ __launch_bounds__(256) void prep_kernel(
    const float* __restrict__ x,
    const float* __restrict__ Wq, const float* __restrict__ Wk,
    const float* __restrict__ Wv, const float* __restrict__ Wo,
    const float* __restrict__ Ws, const float* __restrict__ bs,
    unsigned short* __restrict__ xbf,
    unsigned short* __restrict__ wt, unsigned short* __restrict__ woT,
    float* __restrict__ sigma_out)
{
    const int tid = threadIdx.x;
    int b = blockIdx.x;

    if (b < 1024) {                       // cast x
        int i = b * 256 + tid;
        float4 a = *(const float4*)&x[(size_t)i * 8];
        float4 c = *(const float4*)&x[(size_t)i * 8 + 4];
        union { unsigned short u[8]; int4 v; } o;
        o.u[0] = f2bf(a.x); o.u[1] = f2bf(a.y); o.u[2] = f2bf(a.z); o.u[3] = f2bf(a.w);
        o.u[4] = f2bf(c.x); o.u[5] = f2bf(c.y); o.u[6] = f2bf(c.z); o.u[7] = f2bf(c.w);
        *(int4*)&xbf[(size_t)i * 8] = o.v;
        return;
    }
    b -= 1024;
    if (b < 1024) {                       // transpose 32x32 tile of a weight
        __shared__ float tile[32][33];
        int z = b >> 8, t = b & 255;
        const float* W = (z == 0) ? Wq : (z == 1) ? Wk : (z == 2) ? Wv : Wo;
        unsigned short* dst = (z < 3) ? (wt + (size_t)z * 512 * 512) : woT;
        int k0 = (t >> 4) * 32, n0 = (t & 15) * 32;
        int ty = tid >> 3, tx = tid & 7;
        float4 v = *(const float4*)&W[(size_t)(k0 + ty) * 512 + n0 + tx * 4];
        tile[ty][tx*4+0] = v.x; tile[ty][tx*4+1] = v.y;
        tile[ty][tx*4+2] = v.z; tile[ty][tx*4+3] = v.w;
        __syncthreads();
        ushort4 o;
        o.x = f2bf(tile[tx*4+0][ty]);
        o.y = f2bf(tile[tx*4+1][ty]);
        o.z = f2bf(tile[tx*4+2][ty]);
        o.w = f2bf(tile[tx*4+3][ty]);
        *(ushort4*)&dst[(size_t)(n0 + ty) * 512 + k0 + tx * 4] = o;
        return;
    }
    b -= 1024;
    {                                     // sigma: 32 rows per block, f32
        __shared__ float ws_s[512][8];
        #pragma unroll
        for (int i = 0; i < 16; ++i) {
            int idx = i * 256 + tid;
            ws_s[idx >> 3][idx & 7] = Ws[idx];
        }
        __syncthreads();
        int row = b * 32 + (tid >> 3);
        int col = tid & 7;
        float acc = 0.f;
        #pragma unroll
        for (int k = 0; k < 512; k += 4) {
            float4 xv = *(const float4*)&x[(size_t)row * 512 + k];
            acc += xv.x * ws_s[k][col] + xv.y * ws_s[k+1][col]
                 + xv.z * ws_s[k+2][col] + xv.w * ws_s[k+3][col];
        }
        float z = acc + bs[col];
        int bb = row >> 10, t = row & 1023;
        sigma_out[(size_t)(bb * HH + col) * TT + t] = softplus_f(z) + 1e-6f;
    }
}

// ---------------------------------------------------------------------------
// K1: proj GEMM. Same 128x128 MFMA structure as r9; epilogue now writes K and
// V in fragment-major swizzled layout so attn can load MFMA B-operands
// directly from global, fully coalesced.
// ---------------------------------------------------------------------------
__global__ __launch_bounds__(512) void proj_mfma_kernel(
    const unsigned short* __restrict__ xbf,   // [4096][512]
    const unsigned short* __restrict__ wt,    // [1536][512]
    const float* __restrict__ bq, const float* __restrict__ bk,
    const float* __restrict__ bv,
    unsigned short* __restrict__ qbf, unsigned short* __restrict__ kswz,
    unsigned short* __restrict__ vswz)
{
    __shared__ unsigned short a_s[2][128][64];
    __shared__ unsigned short b_s[2][128][64];
    const int tid = threadIdx.x;
    const int w = tid >> 6, l = tid & 63, lr = l & 15, lg = l >> 4;
    const int wr = (w & 3) * 32;
    const int wc = (w >> 2) * 64;
    const int n0 = blockIdx.x * 128;
    const int m0 = blockIdx.y * 128;

    f32x4 acc[2][4];
    #pragma unroll
    for (int am = 0; am < 2; ++am)
        #pragma unroll
        for (int nb = 0; nb < 4; ++nb) acc[am][nb] = (f32x4){0.f, 0.f, 0.f, 0.f};

    int4 areg[2], breg[2];
    #pragma unroll
    for (int rep = 0; rep < 2; ++rep) {
        int idx = rep * 512 + tid;
        int row = idx >> 3, cg = idx & 7;
        areg[rep] = *(const int4*)&xbf[(size_t)(m0 + row) * 512 + cg * 8];
        breg[rep] = *(const int4*)&wt[(size_t)(n0 + row) * 512 + cg * 8];
    }
    #pragma unroll
    for (int rep = 0; rep < 2; ++rep) {
        int idx = rep * 512 + tid;
        int row = idx >> 3, cg = idx & 7;
        *(int4*)&a_s[0][row][(cg ^ (row & 7)) * 8] = areg[rep];
        *(int4*)&b_s[0][row][(cg ^ (row & 7)) * 8] = breg[rep];
    }
    bar_lgkm();

    for (int kc = 0; kc < 8; ++kc) {
        const int cur = kc & 1;
        if (kc < 7) {
            int k0 = (kc + 1) * 64;
            #pragma unroll
            for (int rep = 0; rep < 2; ++rep) {
                int idx = rep * 512 + tid;
                int row = idx >> 3, cg = idx & 7;
                areg[rep] = *(const int4*)&xbf[(size_t)(m0 + row) * 512 + k0 + cg * 8];
                breg[rep] = *(const int4*)&wt[(size_t)(n0 + row) * 512 + k0 + cg * 8];
            }
        }
        #pragma unroll
        for (int ks = 0; ks < 2; ++ks) {
            bf8_t af[2];
            #pragma unroll
            for (int am = 0; am < 2; ++am) {
                int arow = wr + am * 16 + lr;
                af[am] = *(const bf8_t*)&a_s[cur][arow][((ks*4 + lg) ^ (arow & 7)) * 8];
            }
            #pragma unroll
            for (int nb = 0; nb < 4; ++nb) {
                int brow = wc + nb * 16 + lr;
                bf8_t bf = *(const bf8_t*)&b_s[cur][brow][((ks*4 + lg) ^ (brow & 7)) * 8];
                #pragma unroll
                for (int am = 0; am < 2; ++am)
                    acc[am][nb] = __builtin_amdgcn_mfma_f32_16x16x32_bf16(
                        af[am], bf, acc[am][nb], 0, 0, 0);
            }
        }
        if (kc < 7) {
            #pragma unroll
            for (int rep = 0; rep < 2; ++rep) {
                int idx = rep * 512 + tid;
                int row = idx >> 3, cg = idx & 7;
                *(int4*)&a_s[cur ^ 1][row][(cg ^ (row & 7)) * 8] = areg[rep];
                *(int4*)&b_s[cur ^ 1][row][(cg ^ (row & 7)) * 8] = breg[rep];
            }
            bar_lgkm();
        }
    }

    #pragma unroll
    for (int nb = 0; nb < 4; ++nb) {
        int cl = n0 + wc + nb * 16 + lr;          // 0..1535
        int seg = cl >> 9;
        int i512 = cl & 511;
        int h = i512 >> 6;
        int dh = i512 & 63;
        const float* bias = (seg == 0) ? bq : (seg == 1) ? bk : bv;
        float bb = bias[i512];
        #pragma unroll
        for (int am = 0; am < 2; ++am)
            #pragma unroll
            for (int r = 0; r < 4; ++r) {
                int m = m0 + wr + am * 16 + lg * 4 + r;
                int batch = m >> 10, t = m & 1023;
                size_t bhbase = (size_t)(batch * HH + h) * 65536;
                float v = acc[am][nb][r] + bb;
                if (seg == 0) {
                    qbf[((size_t)(batch*HH + h)*TT + t) * 64 + dh] = f2bf(v * 0.125f);
                } else if (seg == 1) {
                    kswz[bhbase + koff(t, dh)] = f2bf(v);
                } else {
                    vswz[bhbase + voff(t, dh)] = f2bf(v);
                }
            }
    }
}

// ---------------------------------------------------------------------------
// K2: fused attention + prior — BARRIER-FREE. K/V MFMA B-operands are direct
// coalesced global loads from the fragment-major swizzled layouts (1 KB/wave
// per load, L2-resident). Only LDS use is the wave-private P re-layout.
// Grid (bh, qb): all 16 q-blocks of one bh land on the same XCD (bid%8).
// ---------------------------------------------------------------------------
__global__ __launch_bounds__(256) void attn_kernel(
    const unsigned short* __restrict__ qbf,
    const unsigned short* __restrict__ kswz,
    const unsigned short* __restrict__ vswz,
    const float* __restrict__ sigma,
    float* __restrict__ series, float* __restrict__ prior,
    unsigned short* __restrict__ obf)
{
    __shared__ unsigned short p_lds[4][16][72];

    const int tid = threadIdx.x;
    const int w  = tid >> 6, l = tid & 63;
    const int lr = l & 15,  lg = l >> 4;
    const int bh = blockIdx.x;                 // 0..31 (XCD-local per bh)
    const int qr = blockIdx.y * 64 + w * 16;

    const unsigned short* kb = kswz + (size_t)bh * 65536;
    const unsigned short* vb = vswz + (size_t)bh * 65536;

    bf8_t aq[2];
    {
        const unsigned short* qrow = &qbf[((size_t)bh * TT + qr + lr) * 64];
        aq[0] = *(const bf8_t*)&qrow[lg * 8];
        aq[1] = *(const bf8_t*)&qrow[32 + lg * 8];
    }

    // ---------------- sweep 1: row sums (no barriers, no staging) ----------
    float psum[4] = {0.f, 0.f, 0.f, 0.f};
    for (int st = 0; st < 16; ++st) {
        #pragma unroll
        for (int nb = 0; nb < 4; ++nb) {
            f32x4 acc = {0.f, 0.f, 0.f, 0.f};
            #pragma unroll
            for (int c = 0; c < 2; ++c) {
                bf8_t bk = *(const bf8_t*)&kb[(size_t)(((st*4 + nb)*2 + c) << 9) + l*8];
                acc = __builtin_amdgcn_mfma_f32_16x16x32_bf16(aq[c], bk, acc, 0, 0, 0);
            }
            #pragma unroll
            for (int r = 0; r < 4; ++r) psum[r] += __expf(acc[r]);
        }
    }
    #pragma unroll
    for (int r = 0; r < 4; ++r) {
        psum[r] += __shfl_xor(psum[r], 1);
        psum[r] += __shfl_xor(psum[r], 2);
        psum[r] += __shfl_xor(psum[r], 4);
        psum[r] += __shfl_xor(psum[r], 8);
    }
    float inv[4];
    #pragma unroll
    for (int r = 0; r < 4; ++r) inv[r] = 1.f / psum[r];

    // ---------------- sweep 2: series + PV + in-loop prior -----------------
    f32x4 oacc[4];
    #pragma unroll
    for (int nb = 0; nb < 4; ++nb) oacc[nb] = (f32x4){0.f, 0.f, 0.f, 0.f};

    for (int st = 0; st < 16; ++st) {
        #pragma unroll
        for (int nb = 0; nb < 4; ++nb) {
            f32x4 acc = {0.f, 0.f, 0.f, 0.f};
            #pragma unroll
            for (int c = 0; c < 2; ++c) {
                bf8_t bk = *(const bf8_t*)&kb[(size_t)(((st*4 + nb)*2 + c) << 9) + l*8];
                acc = __builtin_amdgcn_mfma_f32_16x16x32_bf16(aq[c], bk, acc, 0, 0, 0);
            }
            #pragma unroll
            for (int r = 0; r < 4; ++r) {
                float e = __expf(acc[r]);
                series[((size_t)bh * TT + qr + lg * 4 + r) * TT + st * 64 + nb * 16 + lr]
                    = e * inv[r];
                p_lds[w][lg * 4 + r][nb * 16 + lr] = f2bf(e);
            }
        }

        bf8_t pa0 = *(const bf8_t*)&p_lds[w][lr][lg * 8];
        bf8_t pa1 = *(const bf8_t*)&p_lds[w][lr][32 + lg * 8];
        #pragma unroll
        for (int nb = 0; nb < 4; ++nb) {
            #pragma unroll
            for (int c = 0; c < 2; ++c) {
                bf8_t bv = *(const bf8_t*)&vb[(size_t)(((st*4 + nb)*2 + c) << 9) + l*8];
                oacc[nb] = __builtin_amdgcn_mfma_f32_16x16x32_bf16(
                    (c == 0) ? pa0 : pa1, bv, oacc[nb], 0, 0, 0);
            }
        }

        // prior row t = qr + st
        {
            int t = qr + st;
            float sg = sigma[(size_t)bh * TT + t];
            float cc = 1.f / (2.f * (sg * sg + 1e-6f));
            float e[16]; float sum = 0.f;
            #pragma unroll
            for (int j = 0; j < 16; ++j) {
                float d = (float)(t - (j * 64 + l));
                e[j] = __expf(-(d * d) * cc);
                sum += e[j];
            }
            sum += __shfl_xor(sum, 32);
            sum += __shfl_xor(sum, 16);
            sum += __shfl_xor(sum, 8);
            sum += __shfl_xor(sum, 4);
            sum += __shfl_xor(sum, 2);
            sum += __shfl_xor(sum, 1);
            float pinv = 1.f / (sum + 1e-9f);
            float* pr = prior + ((size_t)bh * TT + t) * TT;
            #pragma unroll
            for (int j = 0; j < 16; ++j) pr[j * 64 + l] = e[j] * pinv;
        }
    }

    const int b = bh >> 3, h = bh & 7;
    #pragma unroll
    for (int nb = 0; nb < 4; ++nb)
        #pragma unroll
        for (int r = 0; r < 4; ++r) {
            int t = qr + lg * 4 + r;
            obf[((size_t)(b * TT + t)) * 512 + h * 64 + nb * 16 + lr] =
                f2bf(oacc[nb][r] * inv[r]);
        }
}

// ---------------------------------------------------------------------------
// K3: out = obf[4096,512] @ woT^T + bo. 128x128 tile (r9 version, no NT).
// ---------------------------------------------------------------------------
__global__ __launch_bounds__(512) void outproj_mfma_kernel(
    const unsigned short* __restrict__ obf,
    const unsigned short* __restrict__ woT,
    const float* __restrict__ bo, float* __restrict__ out)
{
    __shared__ unsigned short a_s[2][128][64];
    __shared__ unsigned short b_s[2][128][64];
    const int tid = threadIdx.x;
    const int w = tid >> 6, l = tid & 63, lr = l & 15, lg = l >> 4;
    const int wr = (w & 3) * 32;
    const int wc = (w >> 2) * 64;
    const int n0 = blockIdx.x * 128;
    const int m0 = blockIdx.y * 128;

    f32x4 acc[2][4];
    #pragma unroll
    for (int am = 0; am < 2; ++am)
        #pragma unroll
        for (int nb = 0; nb < 4; ++nb) acc[am][nb] = (f32x4){0.f, 0.f, 0.f, 0.f};

    int4 areg[2], breg[2];
    #pragma unroll
    for (int rep = 0; rep < 2; ++rep) {
        int idx = rep * 512 + tid;
        int row = idx >> 3, cg = idx & 7;
        areg[rep] = *(const int4*)&obf[(size_t)(m0 + row) * 512 + cg * 8];
        breg[rep] = *(const int4*)&woT[(size_t)(n0 + row) * 512 + cg * 8];
    }
    #pragma unroll
    for (int rep = 0; rep < 2; ++rep) {
        int idx = rep * 512 + tid;
        int row = idx >> 3, cg = idx & 7;
        *(int4*)&a_s[0][row][(cg ^ (row & 7)) * 8] = areg[rep];
        *(int4*)&b_s[0][row][(cg ^ (row & 7)) * 8] = breg[rep];
    }
    bar_lgkm();

    for (int kc = 0; kc < 8; ++kc) {
        const int cur = kc & 1;
        if (kc < 7) {
            int k0 = (kc + 1) * 64;
            #pragma unroll
            for (int rep = 0; rep < 2; ++rep) {
                int idx = rep * 512 + tid;
                int row = idx >> 3, cg = idx & 7;
                areg[rep] = *(const int4*)&obf[(size_t)(m0 + row) * 512 + k0 + cg * 8];
                breg[rep] = *(const int4*)&woT[(size_t)(n0 + row) * 512 + k0 + cg * 8];
            }
        }
        #pragma unroll
        for (int ks = 0; ks < 2; ++ks) {
            bf8_t af[2];
            #pragma unroll
            for (int am = 0; am < 2; ++am) {
                int arow = wr + am * 16 + lr;
                af[am] = *(const bf8_t*)&a_s[cur][arow][((ks*4 + lg) ^ (arow & 7)) * 8];
            }
            #pragma unroll
            for (int nb = 0; nb < 4; ++nb) {
                int brow = wc + nb * 16 + lr;
                bf8_t bf = *(const bf8_t*)&b_s[cur][brow][((ks*4 + lg) ^ (brow & 7)) * 8];
                #pragma unroll
                for (int am = 0; am < 2; ++am)
                    acc[am][nb] = __builtin_amdgcn_mfma_f32_16x16x32_bf16(
                        af[am], bf, acc[am][nb], 0, 0, 0);
            }
        }
        if (kc < 7) {
            #pragma unroll
            for (int rep = 0; rep < 2; ++rep) {
                int idx = rep * 512 + tid;
                int row = idx >> 3, cg = idx & 7;
                *(int4*)&a_s[cur ^ 1][row][(cg ^ (row & 7)) * 8] = areg[rep];
                *(int4*)&b_s[cur ^ 1][row][(cg ^ (row & 7)) * 8] = breg[rep];
            }
            bar_lgkm();
        }
    }

    #pragma unroll
    for (int nb = 0; nb < 4; ++nb) {
        float bb = bo[n0 + wc + nb * 16 + lr];
        #pragma unroll
        for (int am = 0; am < 2; ++am)
            #pragma unroll
            for (int r = 0; r < 4; ++r) {
                int m = m0 + wr + am * 16 + lg * 4 + r;
                out[(size_t)m * 512 + n0 + wc + nb * 16 + lr] = acc[am][nb][r] + bb;
            }
    }
}

// ---------------------------------------------------------------------------
extern "C" void kernel_launch(void* const* d_in, const int* in_sizes, int n_in,
                              void* d_out, int out_size, void* d_ws, size_t ws_size,
                              hipStream_t stream)
{
    const float* x    = (const float*)d_in[0];
    const float* Wq_w = (const float*)d_in[1];
    const float* Wq_b = (const float*)d_in[2];
    const float* Wk_w = (const float*)d_in[3];
    const float* Wk_b = (const float*)d_in[4];
    const float* Wv_w = (const float*)d_in[5];
    const float* Wv_b = (const float*)d_in[6];
    const float* Ws_w = (const float*)d_in[7];
    const float* Ws_b = (const float*)d_in[8];
    const float* Wo_w = (const float*)d_in[9];
    const float* Wo_b = (const float*)d_in[10];

    float* out    = (float*)d_out;                      // [B,T,D]
    float* series = out + (size_t)BB*TT*DD;             // [B,H,T,T]
    float* prior  = series + (size_t)BB*HH*TT*TT;       // [B,H,T,T]
    float* sigma  = prior + (size_t)BB*HH*TT*TT;        // [B,H,T]

    const size_t nx = (size_t)BB*TT*DD;                 // 2,097,152
    unsigned short* xbf  = (unsigned short*)d_ws;       // [4096][512]
    unsigned short* wt   = xbf + nx;                    // [1536][512]
    unsigned short* woT  = wt + (size_t)1536*512;       // [512][512]
    unsigned short* qbf  = woT + (size_t)512*512;       // [B,H,T,64]
    unsigned short* kswz = qbf + nx;                    // fragment-major
    unsigned short* vswz = kswz + nx;                   // fragment-major
    unsigned short* obf  = vswz + nx;                   // [4096][512]

    prep_kernel<<<2176, 256, 0, stream>>>(
        x, Wq_w, Wk_w, Wv_w, Wo_w, Ws_w, Ws_b, xbf, wt, woT, sigma);

    proj_mfma_kernel<<<dim3(12, 32), 512, 0, stream>>>(
        xbf, wt, Wq_b, Wk_b, Wv_b, qbf, kswz, vswz);

    attn_kernel<<<dim3(32, 16), 256, 0, stream>>>(
        qbf, kswz, vswz, sigma, series, prior, obf);

    outproj_mfma_kernel<<<dim3(4, 32), 512, 0, stream>>>(obf, woT, Wo_b, out);
}

// Round 13
// 109.804 us; speedup vs baseline: 1.3355x; 1.3355x over previous
//
#include <hip/hip_runtime.h>
#include <math.h>

#define BB 4
#define TT 1024
#define DD 512
#define HH 8
#define DHH 64

typedef short bf8_t __attribute__((ext_vector_type(8)));
typedef float f32x4 __attribute__((ext_vector_type(4)));

__device__ __forceinline__ float softplus_f(float z) {
    return fmaxf(z, 0.f) + log1pf(__expf(-fabsf(z)));
}

__device__ __forceinline__ unsigned short f2bf(float f) {
    union { float f; unsigned int u; } v; v.f = f;
    return (unsigned short)((v.u + 0x7FFFu + ((v.u >> 16) & 1u)) >> 16);
}

// Raw barrier: LDS visibility only — does NOT drain vmcnt.
__device__ __forceinline__ void bar_lgkm() {
    asm volatile("s_waitcnt lgkmcnt(0)" ::: "memory");
    __builtin_amdgcn_s_barrier();
}

// ---------------------------------------------------------------------------
// K0: fused prep (cast x, transpose weights, f32 sigma).
// ---------------------------------------------------------------------------
__global__ __launch_bounds__(256) void prep_kernel(
    const float* __restrict__ x,
    const float* __restrict__ Wq, const float* __restrict__ Wk,
    const float* __restrict__ Wv, const float* __restrict__ Wo,
    const float* __restrict__ Ws, const float* __restrict__ bs,
    unsigned short* __restrict__ xbf,
    unsigned short* __restrict__ wt, unsigned short* __restrict__ woT,
    float* __restrict__ sigma_out)
{
    const int tid = threadIdx.x;
    int b = blockIdx.x;

    if (b < 1024) {                       // cast x
        int i = b * 256 + tid;
        float4 a = *(const float4*)&x[(size_t)i * 8];
        float4 c = *(const float4*)&x[(size_t)i * 8 + 4];
        union { unsigned short u[8]; int4 v; } o;
        o.u[0] = f2bf(a.x); o.u[1] = f2bf(a.y); o.u[2] = f2bf(a.z); o.u[3] = f2bf(a.w);
        o.u[4] = f2bf(c.x); o.u[5] = f2bf(c.y); o.u[6] = f2bf(c.z); o.u[7] = f2bf(c.w);
        *(int4*)&xbf[(size_t)i * 8] = o.v;
        return;
    }
    b -= 1024;
    if (b < 1024) {                       // transpose 32x32 tile of a weight
        __shared__ float tile[32][33];
        int z = b >> 8, t = b & 255;
        const float* W = (z == 0) ? Wq : (z == 1) ? Wk : (z == 2) ? Wv : Wo;
        unsigned short* dst = (z < 3) ? (wt + (size_t)z * 512 * 512) : woT;
        int k0 = (t >> 4) * 32, n0 = (t & 15) * 32;
        int ty = tid >> 3, tx = tid & 7;
        float4 v = *(const float4*)&W[(size_t)(k0 + ty) * 512 + n0 + tx * 4];
        tile[ty][tx*4+0] = v.x; tile[ty][tx*4+1] = v.y;
        tile[ty][tx*4+2] = v.z; tile[ty][tx*4+3] = v.w;
        __syncthreads();
        ushort4 o;
        o.x = f2bf(tile[tx*4+0][ty]);
        o.y = f2bf(tile[tx*4+1][ty]);
        o.z = f2bf(tile[tx*4+2][ty]);
        o.w = f2bf(tile[tx*4+3][ty]);
        *(ushort4*)&dst[(size_t)(n0 + ty) * 512 + k0 + tx * 4] = o;
        return;
    }
    b -= 1024;
    {                                     // sigma: 32 rows per block, f32
        __shared__ float ws_s[512][8];
        #pragma unroll
        for (int i = 0; i < 16; ++i) {
            int idx = i * 256 + tid;
            ws_s[idx >> 3][idx & 7] = Ws[idx];
        }
        __syncthreads();
        int row = b * 32 + (tid >> 3);
        int col = tid & 7;
        float acc = 0.f;
        #pragma unroll
        for (int k = 0; k < 512; k += 4) {
            float4 xv = *(const float4*)&x[(size_t)row * 512 + k];
            acc += xv.x * ws_s[k][col] + xv.y * ws_s[k+1][col]
                 + xv.z * ws_s[k+2][col] + xv.w * ws_s[k+3][col];
        }
        float z = acc + bs[col];
        int bb = row >> 10, t = row & 1023;
        sigma_out[(size_t)(bb * HH + col) * TT + t] = softplus_f(z) + 1e-6f;
    }
}

// ---------------------------------------------------------------------------
// K1: proj GEMM via MFMA: C[4096,1536] = xbf @ wt^T -> q(x0.125)/k/v bf16.
// 128x128 tile, 8 waves, dbuf LDS, lgkm-only barriers. (r9 version)
// ---------------------------------------------------------------------------
__global__ __launch_bounds__(512) void proj_mfma_kernel(
    const unsigned short* __restrict__ xbf,   // [4096][512]
    const unsigned short* __restrict__ wt,    // [1536][512]
    const float* __restrict__ bq, const float* __restrict__ bk,
    const float* __restrict__ bv,
    unsigned short* __restrict__ qbf, unsigned short* __restrict__ kbf,
    unsigned short* __restrict__ vbf)
{
    __shared__ unsigned short a_s[2][128][64];
    __shared__ unsigned short b_s[2][128][64];
    const int tid = threadIdx.x;
    const int w = tid >> 6, l = tid & 63, lr = l & 15, lg = l >> 4;
    const int wr = (w & 3) * 32;
    const int wc = (w >> 2) * 64;
    const int n0 = blockIdx.x * 128;
    const int m0 = blockIdx.y * 128;

    f32x4 acc[2][4];
    #pragma unroll
    for (int am = 0; am < 2; ++am)
        #pragma unroll
        for (int nb = 0; nb < 4; ++nb) acc[am][nb] = (f32x4){0.f, 0.f, 0.f, 0.f};

    int4 areg[2], breg[2];
    #pragma unroll
    for (int rep = 0; rep < 2; ++rep) {
        int idx = rep * 512 + tid;
        int row = idx >> 3, cg = idx & 7;
        areg[rep] = *(const int4*)&xbf[(size_t)(m0 + row) * 512 + cg * 8];
        breg[rep] = *(const int4*)&wt[(size_t)(n0 + row) * 512 + cg * 8];
    }
    #pragma unroll
    for (int rep = 0; rep < 2; ++rep) {
        int idx = rep * 512 + tid;
        int row = idx >> 3, cg = idx & 7;
        *(int4*)&a_s[0][row][(cg ^ (row & 7)) * 8] = areg[rep];
        *(int4*)&b_s[0][row][(cg ^ (row & 7)) * 8] = breg[rep];
    }
    bar_lgkm();

    for (int kc = 0; kc < 8; ++kc) {
        const int cur = kc & 1;
        if (kc < 7) {
            int k0 = (kc + 1) * 64;
            #pragma unroll
            for (int rep = 0; rep < 2; ++rep) {
                int idx = rep * 512 + tid;
                int row = idx >> 3, cg = idx & 7;
                areg[rep] = *(const int4*)&xbf[(size_t)(m0 + row) * 512 + k0 + cg * 8];
                breg[rep] = *(const int4*)&wt[(size_t)(n0 + row) * 512 + k0 + cg * 8];
            }
        }
        #pragma unroll
        for (int ks = 0; ks < 2; ++ks) {
            bf8_t af[2];
            #pragma unroll
            for (int am = 0; am < 2; ++am) {
                int arow = wr + am * 16 + lr;
                af[am] = *(const bf8_t*)&a_s[cur][arow][((ks*4 + lg) ^ (arow & 7)) * 8];
            }
            #pragma unroll
            for (int nb = 0; nb < 4; ++nb) {
                int brow = wc + nb * 16 + lr;
                bf8_t bf = *(const bf8_t*)&b_s[cur][brow][((ks*4 + lg) ^ (brow & 7)) * 8];
                #pragma unroll
                for (int am = 0; am < 2; ++am)
                    acc[am][nb] = __builtin_amdgcn_mfma_f32_16x16x32_bf16(
                        af[am], bf, acc[am][nb], 0, 0, 0);
            }
        }
        if (kc < 7) {
            #pragma unroll
            for (int rep = 0; rep < 2; ++rep) {
                int idx = rep * 512 + tid;
                int row = idx >> 3, cg = idx & 7;
                *(int4*)&a_s[cur ^ 1][row][(cg ^ (row & 7)) * 8] = areg[rep];
                *(int4*)&b_s[cur ^ 1][row][(cg ^ (row & 7)) * 8] = breg[rep];
            }
            bar_lgkm();
        }
    }

    #pragma unroll
    for (int nb = 0; nb < 4; ++nb) {
        int cl = n0 + wc + nb * 16 + lr;          // 0..1535
        int seg = cl >> 9;
        int i512 = cl & 511;
        int h = i512 >> 6;
        const float* bias = (seg == 0) ? bq : (seg == 1) ? bk : bv;
        unsigned short* dst = (seg == 0) ? qbf : (seg == 1) ? kbf : vbf;
        const float sc = (seg == 0) ? 0.125f : 1.f;
        float bb = bias[i512];
        #pragma unroll
        for (int am = 0; am < 2; ++am)
            #pragma unroll
            for (int r = 0; r < 4; ++r) {
                int m = m0 + wr + am * 16 + lg * 4 + r;
                int batch = m >> 10, t = m & 1023;
                dst[((size_t)((batch*HH + h)*TT + t)) * 64 + (i512 & 63)] =
                    f2bf((acc[am][nb][r] + bb) * sc);
            }
    }
}

// ---------------------------------------------------------------------------
// K2: fused attention + prior. r7-validated LDS-staged dbuf structure, now
// with 8 waves / 512 threads / 128 q-rows per block: staged K/V tiles serve
// 8 waves, K/V global re-reads halve, barrier instances per q-row halve.
// ---------------------------------------------------------------------------
__global__ __launch_bounds__(512) void attn_kernel(
    const unsigned short* __restrict__ qbf,
    const unsigned short* __restrict__ kbf,
    const unsigned short* __restrict__ vbf,
    const float* __restrict__ sigma,
    float* __restrict__ series, float* __restrict__ prior,
    unsigned short* __restrict__ obf)
{
    __shared__ unsigned short k_lds[2][64][72];   // K tile [s][dh], dbuf
    __shared__ unsigned short v_lds[2][64][64];   // V^T tile [dh][s] swizzled, dbuf
    __shared__ unsigned short p_lds[8][16][72];   // per-wave P tile [qrow][s]

    const int tid = threadIdx.x;
    const int w  = tid >> 6, l = tid & 63;
    const int lr = l & 15,  lg = l >> 4;
    const int bh = blockIdx.y;
    const int qr = blockIdx.x * 128 + w * 16;     // wave's 16 q-rows

    const int srow = tid >> 3, scg = tid & 7;     // staging: row 0..63, one int4
    const unsigned short* kb = kbf + (size_t)bh * TT * 64;
    const unsigned short* vb = vbf + (size_t)bh * TT * 64;

    bf8_t aq[2];
    {
        const unsigned short* qrow = &qbf[((size_t)bh * TT + qr + lr) * 64];
        aq[0] = *(const bf8_t*)&qrow[lg * 8];
        aq[1] = *(const bf8_t*)&qrow[32 + lg * 8];
    }

    int4 kreg, vreg;

    // ---------------- sweep 1: row sums ----------------
    float psum[4] = {0.f, 0.f, 0.f, 0.f};
    kreg = *(const int4*)&kb[(size_t)srow * 64 + scg * 8];
    *(int4*)&k_lds[0][srow][scg * 8] = kreg;
    bar_lgkm();

    for (int st = 0; st < 16; ++st) {
        const int cur = st & 1;
        if (st < 15)
            kreg = *(const int4*)&kb[(size_t)((st+1)*64 + srow) * 64 + scg * 8];
        #pragma unroll
        for (int nb = 0; nb < 4; ++nb) {
            f32x4 acc = {0.f, 0.f, 0.f, 0.f};
            #pragma unroll
            for (int c = 0; c < 2; ++c) {
                bf8_t bk = *(const bf8_t*)&k_lds[cur][nb * 16 + lr][c * 32 + lg * 8];
                acc = __builtin_amdgcn_mfma_f32_16x16x32_bf16(aq[c], bk, acc, 0, 0, 0);
            }
            #pragma unroll
            for (int r = 0; r < 4; ++r) psum[r] += __expf(acc[r]);
        }
        if (st < 15) {
            *(int4*)&k_lds[cur ^ 1][srow][scg * 8] = kreg;
            bar_lgkm();
        }
    }
    #pragma unroll
    for (int r = 0; r < 4; ++r) {
        psum[r] += __shfl_xor(psum[r], 1);
        psum[r] += __shfl_xor(psum[r], 2);
        psum[r] += __shfl_xor(psum[r], 4);
        psum[r] += __shfl_xor(psum[r], 8);
    }
    float inv[4];
    #pragma unroll
    for (int r = 0; r < 4; ++r) inv[r] = 1.f / psum[r];

    // ---------------- sweep 2: series + PV + in-loop prior ----------------
    f32x4 oacc[4];
    #pragma unroll
    for (int nb = 0; nb < 4; ++nb) oacc[nb] = (f32x4){0.f, 0.f, 0.f, 0.f};

    kreg = *(const int4*)&kb[(size_t)srow * 64 + scg * 8];
    vreg = *(const int4*)&vb[(size_t)srow * 64 + scg * 8];
    *(int4*)&k_lds[0][srow][scg * 8] = kreg;
    {
        const unsigned short* pv = (const unsigned short*)&vreg;
        #pragma unroll
        for (int j = 0; j < 8; ++j) {
            int row = scg * 8 + j;
            int g0 = ((srow >> 3) ^ j ^ scg) & 7;
            v_lds[0][row][g0 * 8 + (srow & 7)] = pv[j];
        }
    }
    bar_lgkm();

    for (int st = 0; st < 16; ++st) {
        const int cur = st & 1;
        if (st < 15) {
            kreg = *(const int4*)&kb[(size_t)((st+1)*64 + srow) * 64 + scg * 8];
            vreg = *(const int4*)&vb[(size_t)((st+1)*64 + srow) * 64 + scg * 8];
        }

        #pragma unroll
        for (int nb = 0; nb < 4; ++nb) {
            f32x4 acc = {0.f, 0.f, 0.f, 0.f};
            #pragma unroll
            for (int c = 0; c < 2; ++c) {
                bf8_t bk = *(const bf8_t*)&k_lds[cur][nb * 16 + lr][c * 32 + lg * 8];
                acc = __builtin_amdgcn_mfma_f32_16x16x32_bf16(aq[c], bk, acc, 0, 0, 0);
            }
            #pragma unroll
            for (int r = 0; r < 4; ++r) {
                float e = __expf(acc[r]);
                series[((size_t)bh * TT + qr + lg * 4 + r) * TT + st * 64 + nb * 16 + lr]
                    = e * inv[r];
                p_lds[w][lg * 4 + r][nb * 16 + lr] = f2bf(e);
            }
        }

        bf8_t pa0 = *(const bf8_t*)&p_lds[w][lr][lg * 8];
        bf8_t pa1 = *(const bf8_t*)&p_lds[w][lr][32 + lg * 8];
        #pragma unroll
        for (int nb = 0; nb < 4; ++nb) {
            #pragma unroll
            for (int c = 0; c < 2; ++c) {
                int row = nb * 16 + lr;
                int gsw = ((c * 4 + lg) ^ (row & 7) ^ (row >> 3)) & 7;
                bf8_t bv = *(const bf8_t*)&v_lds[cur][row][gsw * 8];
                oacc[nb] = __builtin_amdgcn_mfma_f32_16x16x32_bf16(
                    (c == 0) ? pa0 : pa1, bv, oacc[nb], 0, 0, 0);
            }
        }

        // prior row t = qr + st (each wave covers its own 16 rows over 16 st)
        {
            int t = qr + st;
            float sg = sigma[(size_t)bh * TT + t];
            float cc = 1.f / (2.f * (sg * sg + 1e-6f));
            float e[16]; float sum = 0.f;
            #pragma unroll
            for (int j = 0; j < 16; ++j) {
                float d = (float)(t - (j * 64 + l));
                e[j] = __expf(-(d * d) * cc);
                sum += e[j];
            }
            sum += __shfl_xor(sum, 32);
            sum += __shfl_xor(sum, 16);
            sum += __shfl_xor(sum, 8);
            sum += __shfl_xor(sum, 4);
            sum += __shfl_xor(sum, 2);
            sum += __shfl_xor(sum, 1);
            float pinv = 1.f / (sum + 1e-9f);
            float* pr = prior + ((size_t)bh * TT + t) * TT;
            #pragma unroll
            for (int j = 0; j < 16; ++j) pr[j * 64 + l] = e[j] * pinv;
        }

        if (st < 15) {
            *(int4*)&k_lds[cur ^ 1][srow][scg * 8] = kreg;
            const unsigned short* pv = (const unsigned short*)&vreg;
            #pragma unroll
            for (int j = 0; j < 8; ++j) {
                int row = scg * 8 + j;
                int g0 = ((srow >> 3) ^ j ^ scg) & 7;
                v_lds[cur ^ 1][row][g0 * 8 + (srow & 7)] = pv[j];
            }
            bar_lgkm();
        }
    }

    const int b = bh >> 3, h = bh & 7;
    #pragma unroll
    for (int nb = 0; nb < 4; ++nb)
        #pragma unroll
        for (int r = 0; r < 4; ++r) {
            int t = qr + lg * 4 + r;
            obf[((size_t)(b * TT + t)) * 512 + h * 64 + nb * 16 + lr] =
                f2bf(oacc[nb][r] * inv[r]);
        }
}

// ---------------------------------------------------------------------------
// K3: out = obf[4096,512] @ woT^T + bo. 128x128 tile, 8 waves. (r9 version)
// ---------------------------------------------------------------------------
__global__ __launch_bounds__(512) void outproj_mfma_kernel(
    const unsigned short* __restrict__ obf,
    const unsigned short* __restrict__ woT,
    const float* __restrict__ bo, float* __restrict__ out)
{
    __shared__ unsigned short a_s[2][128][64];
    __shared__ unsigned short b_s[2][128][64];
    const int tid = threadIdx.x;
    const int w = tid >> 6, l = tid & 63, lr = l & 15, lg = l >> 4;
    const int wr = (w & 3) * 32;
    const int wc = (w >> 2) * 64;
    const int n0 = blockIdx.x * 128;
    const int m0 = blockIdx.y * 128;

    f32x4 acc[2][4];
    #pragma unroll
    for (int am = 0; am < 2; ++am)
        #pragma unroll
        for (int nb = 0; nb < 4; ++nb) acc[am][nb] = (f32x4){0.f, 0.f, 0.f, 0.f};

    int4 areg[2], breg[2];
    #pragma unroll
    for (int rep = 0; rep < 2; ++rep) {
        int idx = rep * 512 + tid;
        int row = idx >> 3, cg = idx & 7;
        areg[rep] = *(const int4*)&obf[(size_t)(m0 + row) * 512 + cg * 8];
        breg[rep] = *(const int4*)&woT[(size_t)(n0 + row) * 512 + cg * 8];
    }
    #pragma unroll
    for (int rep = 0; rep < 2; ++rep) {
        int idx = rep * 512 + tid;
        int row = idx >> 3, cg = idx & 7;
        *(int4*)&a_s[0][row][(cg ^ (row & 7)) * 8] = areg[rep];
        *(int4*)&b_s[0][row][(cg ^ (row & 7)) * 8] = breg[rep];
    }
    bar_lgkm();

    for (int kc = 0; kc < 8; ++kc) {
        const int cur = kc & 1;
        if (kc < 7) {
            int k0 = (kc + 1) * 64;
            #pragma unroll
            for (int rep = 0; rep < 2; ++rep) {
                int idx = rep * 512 + tid;
                int row = idx >> 3, cg = idx & 7;
                areg[rep] = *(const int4*)&obf[(size_t)(m0 + row) * 512 + k0 + cg * 8];
                breg[rep] = *(const int4*)&woT[(size_t)(n0 + row) * 512 + k0 + cg * 8];
            }
        }
        #pragma unroll
        for (int ks = 0; ks < 2; ++ks) {
            bf8_t af[2];
            #pragma unroll
            for (int am = 0; am < 2; ++am) {
                int arow = wr + am * 16 + lr;
                af[am] = *(const bf8_t*)&a_s[cur][arow][((ks*4 + lg) ^ (arow & 7)) * 8];
            }
            #pragma unroll
            for (int nb = 0; nb < 4; ++nb) {
                int brow = wc + nb * 16 + lr;
                bf8_t bf = *(const bf8_t*)&b_s[cur][brow][((ks*4 + lg) ^ (brow & 7)) * 8];
                #pragma unroll
                for (int am = 0; am < 2; ++am)
                    acc[am][nb] = __builtin_amdgcn_mfma_f32_16x16x32_bf16(
                        af[am], bf, acc[am][nb], 0, 0, 0);
            }
        }
        if (kc < 7) {
            #pragma unroll
            for (int rep = 0; rep < 2; ++rep) {
                int idx = rep * 512 + tid;
                int row = idx >> 3, cg = idx & 7;
                *(int4*)&a_s[cur ^ 1][row][(cg ^ (row & 7)) * 8] = areg[rep];
                *(int4*)&b_s[cur ^ 1][row][(cg ^ (row & 7)) * 8] = breg[rep];
            }
            bar_lgkm();
        }
    }

    #pragma unroll
    for (int nb = 0; nb < 4; ++nb) {
        float bb = bo[n0 + wc + nb * 16 + lr];
        #pragma unroll
        for (int am = 0; am < 2; ++am)
            #pragma unroll
            for (int r = 0; r < 4; ++r) {
                int m = m0 + wr + am * 16 + lg * 4 + r;
                out[(size_t)m * 512 + n0 + wc + nb * 16 + lr] = acc[am][nb][r] + bb;
            }
    }
}

// ---------------------------------------------------------------------------
extern "C" void kernel_launch(void* const* d_in, const int* in_sizes, int n_in,
                              void* d_out, int out_size, void* d_ws, size_t ws_size,
                              hipStream_t stream)
{
    const float* x    = (const float*)d_in[0];
    const float* Wq_w = (const float*)d_in[1];
    const float* Wq_b = (const float*)d_in[2];
    const float* Wk_w = (const float*)d_in[3];
    const float* Wk_b = (const float*)d_in[4];
    const float* Wv_w = (const float*)d_in[5];
    const float* Wv_b = (const float*)d_in[6];
    const float* Ws_w = (const float*)d_in[7];
    const float* Ws_b = (const float*)d_in[8];
    const float* Wo_w = (const float*)d_in[9];
    const float* Wo_b = (const float*)d_in[10];

    float* out    = (float*)d_out;                      // [B,T,D]
    float* series = out + (size_t)BB*TT*DD;             // [B,H,T,T]
    float* prior  = series + (size_t)BB*HH*TT*TT;       // [B,H,T,T]
    float* sigma  = prior + (size_t)BB*HH*TT*TT;        // [B,H,T]

    const size_t nx = (size_t)BB*TT*DD;                 // 2,097,152
    unsigned short* xbf = (unsigned short*)d_ws;        // [4096][512]
    unsigned short* wt  = xbf + nx;                     // [1536][512]
    unsigned short* woT = wt + (size_t)1536*512;        // [512][512]
    unsigned short* qbf = woT + (size_t)512*512;        // [B,H,T,64]
    unsigned short* kbf = qbf + nx;
    unsigned short* vbf = kbf + nx;
    unsigned short* obf = vbf + nx;                     // [4096][512]

    prep_kernel<<<2176, 256, 0, stream>>>(
        x, Wq_w, Wk_w, Wv_w, Wo_w, Ws_w, Ws_b, xbf, wt, woT, sigma);

    proj_mfma_kernel<<<dim3(12, 32), 512, 0, stream>>>(
        xbf, wt, Wq_b, Wk_b, Wv_b, qbf, kbf, vbf);

    attn_kernel<<<dim3(8, 32), 512, 0, stream>>>(
        qbf, kbf, vbf, sigma, series, prior, obf);

    outproj_mfma_kernel<<<dim3(4, 32), 512, 0, stream>>>(obf, woT, Wo_b, out);
}

// Round 14
// 106.338 us; speedup vs baseline: 1.3790x; 1.0326x over previous
//
#include <hip/hip_runtime.h>
#include <math.h>

#define BB 4
#define TT 1024
#define DD 512
#define HH 8
#define DHH 64

typedef short bf8_t __attribute__((ext_vector_type(8)));
typedef float f32x4 __attribute__((ext_vector_type(4)));

__device__ __forceinline__ float softplus_f(float z) {
    return fmaxf(z, 0.f) + log1pf(__expf(-fabsf(z)));
}

__device__ __forceinline__ unsigned short f2bf(float f) {
    union { float f; unsigned int u; } v; v.f = f;
    return (unsigned short)((v.u + 0x7FFFu + ((v.u >> 16) & 1u)) >> 16);
}

// Raw barrier: LDS visibility only — does NOT drain vmcnt (global store acks
// stay in flight across it).
__device__ __forceinline__ void bar_lgkm() {
    asm volatile("s_waitcnt lgkmcnt(0)" ::: "memory");
    __builtin_amdgcn_s_barrier();
}

// ---------------------------------------------------------------------------
// K0a: cast x (f32 [4096][512]) -> bf16
// ---------------------------------------------------------------------------
__global__ __launch_bounds__(256) void cast_x_kernel(
    const float* __restrict__ x, unsigned short* __restrict__ xbf)
{
    int i = blockIdx.x * 256 + threadIdx.x;
    float4 a = *(const float4*)&x[(size_t)i * 8];
    float4 b = *(const float4*)&x[(size_t)i * 8 + 4];
    union { unsigned short u[8]; int4 v; } o;
    o.u[0] = f2bf(a.x); o.u[1] = f2bf(a.y); o.u[2] = f2bf(a.z); o.u[3] = f2bf(a.w);
    o.u[4] = f2bf(b.x); o.u[5] = f2bf(b.y); o.u[6] = f2bf(b.z); o.u[7] = f2bf(b.w);
    *(int4*)&xbf[(size_t)i * 8] = o.v;
}

// ---------------------------------------------------------------------------
// K0b: transpose+cast the 512x512 weights into W^T bf16 [n][k].
// z: 0=Wq 1=Wk 2=Wv (-> wt rows z*512..) 3=Wo (-> woT) 4=Ws (-> wt rows 1536..)
// ---------------------------------------------------------------------------
__global__ __launch_bounds__(256) void transpose_w_kernel(
    const float* __restrict__ Wq, const float* __restrict__ Wk,
    const float* __restrict__ Wv, const float* __restrict__ Wo,
    const float* __restrict__ Ws,
    unsigned short* __restrict__ wt, unsigned short* __restrict__ woT)
{
    __shared__ float tile[32][33];
    const int tid = threadIdx.x;
    const int z = blockIdx.z;
    if (z == 4) {
        if (blockIdx.x != 0 || blockIdx.y != 0) return;
        #pragma unroll
        for (int i = 0; i < 16; ++i) {
            int idx = i * 256 + tid;
            int k = idx >> 3, n = idx & 7;
            wt[(size_t)(1536 + n) * 512 + k] = f2bf(Ws[idx]);
        }
        return;
    }
    const float* W = (z == 0) ? Wq : (z == 1) ? Wk : (z == 2) ? Wv : Wo;
    unsigned short* dst = (z < 3) ? (wt + (size_t)z * 512 * 512) : woT;
    const int k0 = blockIdx.x * 32, n0 = blockIdx.y * 32;
    const int ty = tid >> 3, tx = tid & 7;

    float4 v = *(const float4*)&W[(size_t)(k0 + ty) * 512 + n0 + tx * 4];
    tile[ty][tx*4+0] = v.x; tile[ty][tx*4+1] = v.y;
    tile[ty][tx*4+2] = v.z; tile[ty][tx*4+3] = v.w;
    __syncthreads();
    ushort4 o;
    o.x = f2bf(tile[tx*4+0][ty]);
    o.y = f2bf(tile[tx*4+1][ty]);
    o.z = f2bf(tile[tx*4+2][ty]);
    o.w = f2bf(tile[tx*4+3][ty]);
    *(ushort4*)&dst[(size_t)(n0 + ty) * 512 + k0 + tx * 4] = o;
}

// ---------------------------------------------------------------------------
// K1: proj GEMM via MFMA: C[4096,1544] = xbf @ wt^T. (r7 version)
// ---------------------------------------------------------------------------
__global__ __launch_bounds__(256) void proj_mfma_kernel(
    const unsigned short* __restrict__ xbf,
    const unsigned short* __restrict__ wt,
    const float* __restrict__ bq, const float* __restrict__ bk,
    const float* __restrict__ bv, const float* __restrict__ bs,
    unsigned short* __restrict__ qbf, unsigned short* __restrict__ kbf,
    unsigned short* __restrict__ vbf, float* __restrict__ sigma_out)
{
    __shared__ unsigned short a_s[64][64];
    __shared__ unsigned short b_s[64][64];
    const int tid = threadIdx.x;
    const int w = tid >> 6, l = tid & 63, lr = l & 15, lg = l >> 4;
    const int ct = blockIdx.x;
    const int m0 = blockIdx.y * 64;
    const int n0 = ct * 64;

    f32x4 acc[4];
    #pragma unroll
    for (int nb = 0; nb < 4; ++nb) acc[nb] = (f32x4){0.f, 0.f, 0.f, 0.f};

    for (int k0 = 0; k0 < 512; k0 += 64) {
        __syncthreads();
        #pragma unroll
        for (int rep = 0; rep < 2; ++rep) {
            int idx = rep * 256 + tid;
            int row = idx >> 3, cg = idx & 7;
            *(int4*)&a_s[row][(cg ^ (row & 7)) * 8] =
                *(const int4*)&xbf[(size_t)(m0 + row) * 512 + k0 + cg * 8];
            *(int4*)&b_s[row][(cg ^ (row & 7)) * 8] =
                *(const int4*)&wt[(size_t)(n0 + row) * 512 + k0 + cg * 8];
        }
        __syncthreads();
        #pragma unroll
        for (int ks = 0; ks < 2; ++ks) {
            int arow = w * 16 + lr;
            bf8_t af = *(const bf8_t*)&a_s[arow][((ks*4 + lg) ^ (arow & 7)) * 8];
            #pragma unroll
            for (int nb = 0; nb < 4; ++nb) {
                int brow = nb * 16 + lr;
                bf8_t bf = *(const bf8_t*)&b_s[brow][((ks*4 + lg) ^ (brow & 7)) * 8];
                acc[nb] = __builtin_amdgcn_mfma_f32_16x16x32_bf16(af, bf, acc[nb], 0, 0, 0);
            }
        }
    }

    if (ct < 24) {
        const int seg = ct >> 3;
        const int h = ct & 7;
        const float* bias = (seg == 0) ? bq : (seg == 1) ? bk : bv;
        unsigned short* dst = (seg == 0) ? qbf : (seg == 1) ? kbf : vbf;
        const float sc = (seg == 0) ? 0.125f : 1.f;
        #pragma unroll
        for (int nb = 0; nb < 4; ++nb) {
            float bb = bias[h * 64 + nb * 16 + lr];
            #pragma unroll
            for (int r = 0; r < 4; ++r) {
                int m = m0 + w * 16 + lg * 4 + r;
                int b = m >> 10, t = m & 1023;
                dst[((size_t)((b*HH + h)*TT + t)) * 64 + nb * 16 + lr] =
                    f2bf((acc[nb][r] + bb) * sc);
            }
        }
    } else if (lr < 8) {
        float bb = bs[lr];
        #pragma unroll
        for (int r = 0; r < 4; ++r) {
            int m = m0 + w * 16 + lg * 4 + r;
            int b = m >> 10, t = m & 1023;
            sigma_out[(size_t)(b*HH + lr)*TT + t] = softplus_f(acc[0][r] + bb) + 1e-6f;
        }
    }
}

// ---------------------------------------------------------------------------
// K2: fused attention + prior. Exact r7 structure (4 waves, dbuf LDS,
// lgkm-only barriers, in-loop prior). ONLY change: grid swapped so
// blockIdx.x = bh -> all 16 q-tiles of one bh map to the same XCD (bid%8 =
// bh%8), shrinking the per-XCD K/V working set from ~8 MB to ~1 MB (L2-fit).
// ---------------------------------------------------------------------------
__global__ __launch_bounds__(256) void attn_kernel(
    const unsigned short* __restrict__ qbf,
    const unsigned short* __restrict__ kbf,
    const unsigned short* __restrict__ vbf,
    const float* __restrict__ sigma,
    float* __restrict__ series, float* __restrict__ prior,
    unsigned short* __restrict__ obf)
{
    __shared__ unsigned short k_lds[2][64][72];
    __shared__ unsigned short v_lds[2][64][64];
    __shared__ unsigned short p_lds[4][16][72];

    const int tid = threadIdx.x;
    const int w  = tid >> 6, l = tid & 63;
    const int lr = l & 15,  lg = l >> 4;
    const int bh = blockIdx.x;                 // XCD-local per bh
    const int qr = blockIdx.y * 64 + w * 16;

    const int srow = tid >> 3, scg = tid & 7;
    const unsigned short* kb = kbf + (size_t)bh * TT * 64;
    const unsigned short* vb = vbf + (size_t)bh * TT * 64;

    bf8_t aq[2];
    {
        const unsigned short* qrow = &qbf[((size_t)bh * TT + qr + lr) * 64];
        aq[0] = *(const bf8_t*)&qrow[lg * 8];
        aq[1] = *(const bf8_t*)&qrow[32 + lg * 8];
    }

    int4 kreg0, kreg1, vreg0, vreg1;

    // ---------------- sweep 1: row sums ----------------
    float psum[4] = {0.f, 0.f, 0.f, 0.f};
    kreg0 = *(const int4*)&kb[(size_t)srow * 64 + scg * 8];
    kreg1 = *(const int4*)&kb[(size_t)(32 + srow) * 64 + scg * 8];
    *(int4*)&k_lds[0][srow][scg * 8] = kreg0;
    *(int4*)&k_lds[0][32 + srow][scg * 8] = kreg1;
    bar_lgkm();

    for (int st = 0; st < 16; ++st) {
        const int cur = st & 1;
        if (st < 15) {
            kreg0 = *(const int4*)&kb[(size_t)((st+1)*64 + srow) * 64 + scg * 8];
            kreg1 = *(const int4*)&kb[(size_t)((st+1)*64 + 32 + srow) * 64 + scg * 8];
        }
        #pragma unroll
        for (int nb = 0; nb < 4; ++nb) {
            f32x4 acc = {0.f, 0.f, 0.f, 0.f};
            #pragma unroll
            for (int c = 0; c < 2; ++c) {
                bf8_t bk = *(const bf8_t*)&k_lds[cur][nb * 16 + lr][c * 32 + lg * 8];
                acc = __builtin_amdgcn_mfma_f32_16x16x32_bf16(aq[c], bk, acc, 0, 0, 0);
            }
            #pragma unroll
            for (int r = 0; r < 4; ++r) psum[r] += __expf(acc[r]);
        }
        if (st < 15) {
            *(int4*)&k_lds[cur ^ 1][srow][scg * 8] = kreg0;
            *(int4*)&k_lds[cur ^ 1][32 + srow][scg * 8] = kreg1;
            bar_lgkm();
        }
    }
    #pragma unroll
    for (int r = 0; r < 4; ++r) {
        psum[r] += __shfl_xor(psum[r], 1);
        psum[r] += __shfl_xor(psum[r], 2);
        psum[r] += __shfl_xor(psum[r], 4);
        psum[r] += __shfl_xor(psum[r], 8);
    }
    float inv[4];
    #pragma unroll
    for (int r = 0; r < 4; ++r) inv[r] = 1.f / psum[r];

    // ---------------- sweep 2: series + PV + in-loop prior ----------------
    f32x4 oacc[4];
    #pragma unroll
    for (int nb = 0; nb < 4; ++nb) oacc[nb] = (f32x4){0.f, 0.f, 0.f, 0.f};

    kreg0 = *(const int4*)&kb[(size_t)srow * 64 + scg * 8];
    kreg1 = *(const int4*)&kb[(size_t)(32 + srow) * 64 + scg * 8];
    vreg0 = *(const int4*)&vb[(size_t)srow * 64 + scg * 8];
    vreg1 = *(const int4*)&vb[(size_t)(32 + srow) * 64 + scg * 8];
    *(int4*)&k_lds[0][srow][scg * 8] = kreg0;
    *(int4*)&k_lds[0][32 + srow][scg * 8] = kreg1;
    {
        const unsigned short* pv0 = (const unsigned short*)&vreg0;
        const unsigned short* pv1 = (const unsigned short*)&vreg1;
        #pragma unroll
        for (int j = 0; j < 8; ++j) {
            int row = scg * 8 + j;
            int g0 = ((srow >> 3) ^ j ^ scg) & 7;
            int g1 = ((srow >> 3) ^ 4 ^ j ^ scg) & 7;
            v_lds[0][row][g0 * 8 + (srow & 7)] = pv0[j];
            v_lds[0][row][g1 * 8 + (srow & 7)] = pv1[j];
        }
    }
    bar_lgkm();

    for (int st = 0; st < 16; ++st) {
        const int cur = st & 1;
        if (st < 15) {
            kreg0 = *(const int4*)&kb[(size_t)((st+1)*64 + srow) * 64 + scg * 8];
            kreg1 = *(const int4*)&kb[(size_t)((st+1)*64 + 32 + srow) * 64 + scg * 8];
            vreg0 = *(const int4*)&vb[(size_t)((st+1)*64 + srow) * 64 + scg * 8];
            vreg1 = *(const int4*)&vb[(size_t)((st+1)*64 + 32 + srow) * 64 + scg * 8];
        }

        #pragma unroll
        for (int nb = 0; nb < 4; ++nb) {
            f32x4 acc = {0.f, 0.f, 0.f, 0.f};
            #pragma unroll
            for (int c = 0; c < 2; ++c) {
                bf8_t bk = *(const bf8_t*)&k_lds[cur][nb * 16 + lr][c * 32 + lg * 8];
                acc = __builtin_amdgcn_mfma_f32_16x16x32_bf16(aq[c], bk, acc, 0, 0, 0);
            }
            #pragma unroll
            for (int r = 0; r < 4; ++r) {
                float e = __expf(acc[r]);
                series[((size_t)bh * TT + qr + lg * 4 + r) * TT + st * 64 + nb * 16 + lr]
                    = e * inv[r];
                p_lds[w][lg * 4 + r][nb * 16 + lr] = f2bf(e);
            }
        }

        bf8_t pa0 = *(const bf8_t*)&p_lds[w][lr][lg * 8];
        bf8_t pa1 = *(const bf8_t*)&p_lds[w][lr][32 + lg * 8];
        #pragma unroll
        for (int nb = 0; nb < 4; ++nb) {
            #pragma unroll
            for (int c = 0; c < 2; ++c) {
                int row = nb * 16 + lr;
                int gsw = ((c * 4 + lg) ^ (row & 7) ^ (row >> 3)) & 7;
                bf8_t bv = *(const bf8_t*)&v_lds[cur][row][gsw * 8];
                oacc[nb] = __builtin_amdgcn_mfma_f32_16x16x32_bf16(
                    (c == 0) ? pa0 : pa1, bv, oacc[nb], 0, 0, 0);
            }
        }

        {
            int t = qr + st;
            float sg = sigma[(size_t)bh * TT + t];
            float cc = 1.f / (2.f * (sg * sg + 1e-6f));
            float e[16]; float sum = 0.f;
            #pragma unroll
            for (int j = 0; j < 16; ++j) {
                float d = (float)(t - (j * 64 + l));
                e[j] = __expf(-(d * d) * cc);
                sum += e[j];
            }
            sum += __shfl_xor(sum, 32);
            sum += __shfl_xor(sum, 16);
            sum += __shfl_xor(sum, 8);
            sum += __shfl_xor(sum, 4);
            sum += __shfl_xor(sum, 2);
            sum += __shfl_xor(sum, 1);
            float pinv = 1.f / (sum + 1e-9f);
            float* pr = prior + ((size_t)bh * TT + t) * TT;
            #pragma unroll
            for (int j = 0; j < 16; ++j) pr[j * 64 + l] = e[j] * pinv;
        }

        if (st < 15) {
            *(int4*)&k_lds[cur ^ 1][srow][scg * 8] = kreg0;
            *(int4*)&k_lds[cur ^ 1][32 + srow][scg * 8] = kreg1;
            const unsigned short* pv0 = (const unsigned short*)&vreg0;
            const unsigned short* pv1 = (const unsigned short*)&vreg1;
            #pragma unroll
            for (int j = 0; j < 8; ++j) {
                int row = scg * 8 + j;
                int g0 = ((srow >> 3) ^ j ^ scg) & 7;
                int g1 = ((srow >> 3) ^ 4 ^ j ^ scg) & 7;
                v_lds[cur ^ 1][row][g0 * 8 + (srow & 7)] = pv0[j];
                v_lds[cur ^ 1][row][g1 * 8 + (srow & 7)] = pv1[j];
            }
            bar_lgkm();
        }
    }

    const int b = bh >> 3, h = bh & 7;
    #pragma unroll
    for (int nb = 0; nb < 4; ++nb)
        #pragma unroll
        for (int r = 0; r < 4; ++r) {
            int t = qr + lg * 4 + r;
            obf[((size_t)(b * TT + t)) * 512 + h * 64 + nb * 16 + lr] =
                f2bf(oacc[nb][r] * inv[r]);
        }
}

// ---------------------------------------------------------------------------
// K3: out = obf[4096,512] @ woT^T + bo (MFMA), f32 out. (r7 version)
// ---------------------------------------------------------------------------
__global__ __launch_bounds__(256) void outproj_mfma_kernel(
    const unsigned short* __restrict__ obf,
    const unsigned short* __restrict__ woT,
    const float* __restrict__ bo, float* __restrict__ out)
{
    __shared__ unsigned short a_s[64][64];
    __shared__ unsigned short b_s[64][64];
    const int tid = threadIdx.x;
    const int w = tid >> 6, l = tid & 63, lr = l & 15, lg = l >> 4;
    const int n0 = blockIdx.x * 64;
    const int m0 = blockIdx.y * 64;

    f32x4 acc[4];
    #pragma unroll
    for (int nb = 0; nb < 4; ++nb) acc[nb] = (f32x4){0.f, 0.f, 0.f, 0.f};

    for (int k0 = 0; k0 < 512; k0 += 64) {
        __syncthreads();
        #pragma unroll
        for (int rep = 0; rep < 2; ++rep) {
            int idx = rep * 256 + tid;
            int row = idx >> 3, cg = idx & 7;
            *(int4*)&a_s[row][(cg ^ (row & 7)) * 8] =
                *(const int4*)&obf[(size_t)(m0 + row) * 512 + k0 + cg * 8];
            *(int4*)&b_s[row][(cg ^ (row & 7)) * 8] =
                *(const int4*)&woT[(size_t)(n0 + row) * 512 + k0 + cg * 8];
        }
        __syncthreads();
        #pragma unroll
        for (int ks = 0; ks < 2; ++ks) {
            int arow = w * 16 + lr;
            bf8_t af = *(const bf8_t*)&a_s[arow][((ks*4 + lg) ^ (arow & 7)) * 8];
            #pragma unroll
            for (int nb = 0; nb < 4; ++nb) {
                int brow = nb * 16 + lr;
                bf8_t bf = *(const bf8_t*)&b_s[brow][((ks*4 + lg) ^ (brow & 7)) * 8];
                acc[nb] = __builtin_amdgcn_mfma_f32_16x16x32_bf16(af, bf, acc[nb], 0, 0, 0);
            }
        }
    }

    #pragma unroll
    for (int nb = 0; nb < 4; ++nb) {
        float bb = bo[n0 + nb * 16 + lr];
        #pragma unroll
        for (int r = 0; r < 4; ++r) {
            int m = m0 + w * 16 + lg * 4 + r;
            out[(size_t)m * 512 + n0 + nb * 16 + lr] = acc[nb][r] + bb;
        }
    }
}

// ---------------------------------------------------------------------------
extern "C" void kernel_launch(void* const* d_in, const int* in_sizes, int n_in,
                              void* d_out, int out_size, void* d_ws, size_t ws_size,
                              hipStream_t stream)
{
    const float* x    = (const float*)d_in[0];
    const float* Wq_w = (const float*)d_in[1];
    const float* Wq_b = (const float*)d_in[2];
    const float* Wk_w = (const float*)d_in[3];
    const float* Wk_b = (const float*)d_in[4];
    const float* Wv_w = (const float*)d_in[5];
    const float* Wv_b = (const float*)d_in[6];
    const float* Ws_w = (const float*)d_in[7];
    const float* Ws_b = (const float*)d_in[8];
    const float* Wo_w = (const float*)d_in[9];
    const float* Wo_b = (const float*)d_in[10];

    float* out    = (float*)d_out;                      // [B,T,D]
    float* series = out + (size_t)BB*TT*DD;             // [B,H,T,T]
    float* prior  = series + (size_t)BB*HH*TT*TT;       // [B,H,T,T]
    float* sigma  = prior + (size_t)BB*HH*TT*TT;        // [B,H,T]

    const size_t nx = (size_t)BB*TT*DD;                 // 2,097,152
    unsigned short* xbf = (unsigned short*)d_ws;        // [4096][512]
    unsigned short* wt  = xbf + nx;                     // [1600][512]
    unsigned short* woT = wt + (size_t)1600*512;        // [512][512]
    unsigned short* qbf = woT + (size_t)512*512;        // [B,H,T,64]
    unsigned short* kbf = qbf + nx;
    unsigned short* vbf = kbf + nx;
    unsigned short* obf = vbf + nx;                     // [4096][512]

    cast_x_kernel<<<1024, 256, 0, stream>>>(x, xbf);
    transpose_w_kernel<<<dim3(16, 16, 5), 256, 0, stream>>>(
        Wq_w, Wk_w, Wv_w, Wo_w, Ws_w, wt, woT);

    proj_mfma_kernel<<<dim3(25, 64), 256, 0, stream>>>(
        xbf, wt, Wq_b, Wk_b, Wv_b, Ws_b, qbf, kbf, vbf, sigma);

    attn_kernel<<<dim3(32, 16), 256, 0, stream>>>(
        qbf, kbf, vbf, sigma, series, prior, obf);

    outproj_mfma_kernel<<<dim3(8, 64), 256, 0, stream>>>(obf, woT, Wo_b, out);
}